// Round 12
// baseline (713.335 us; speedup 1.0000x reference)
//
#include <hip/hip_runtime.h>
#include <hip/hip_bf16.h>

// CapsNet forward. Round 12: conv2+pool restructured to 1-barrier form —
// P1t patch staged in LDS once per block (10x42x72), A read from global
// (L2-hot), whole K=576 loop barrier-free. K-order unchanged => P2t
// bit-identical => absmax must stay exactly 9.155273e-5.
// Rest byte-identical to round 11. B=256, R=1152, C=10, O=16, I=8

typedef __bf16 bf16x8 __attribute__((ext_vector_type(8)));
typedef float  f32x4  __attribute__((ext_vector_type(4)));
typedef ushort u16x8  __attribute__((ext_vector_type(8)));

static __device__ __forceinline__ ushort f2bf(float f) {
    __hip_bfloat16 h = __float2bfloat16(f);
    return *(ushort*)&h;
}
static __device__ __forceinline__ float b2f(ushort u) {
    return __uint_as_float(((unsigned)u) << 16);
}

// ---------------- fused weight prep: Awt | Wt | Aw2 | Aw1 ------------------------
__global__ __launch_bounds__(256) void k_prep_all(
    const float* __restrict__ w1, const float* __restrict__ w2,
    const float* __restrict__ pw, const float* __restrict__ W,
    __hip_bfloat16* __restrict__ Aw1, __hip_bfloat16* __restrict__ Aw2,
    __hip_bfloat16* __restrict__ Awt, __hip_bfloat16* __restrict__ Wt)
{
    int t = blockIdx.x * 256 + threadIdx.x;              // 4,204,544 threads
    if (t < 2654208) {
        int oc = t / 10368, rem = t % 10368;
        int k81 = rem >> 7, ic = rem & 127;
        Awt[t] = __float2bfloat16(pw[(oc * 128 + ic) * 81 + k81]);
    } else if (t < 4128768) {
        int q = t - 2654208;
        int k = q / 160, co = q % 160;
        int r = k >> 3, i = k & 7, c = co >> 4, o = co & 15;
        Wt[q] = __float2bfloat16(W[(((size_t)r * 10 + c) * 16 + o) * 8 + i]);
    } else if (t < 4202496) {
        int q = t - 4128768;
        int oc = q / 576, rem = q % 576;
        int k9 = rem >> 6, ic = rem & 63;
        Aw2[q] = __float2bfloat16(w2[(oc * 64 + ic) * 9 + k9]);
    } else {
        int q = t - 4202496;
        int oc = q >> 5, k = q & 31;
        Aw1[q] = __float2bfloat16(k < 27 ? w1[oc * 27 + k] : 0.f);
    }
}

// ---------------- conv1(3->64,3x3,s1,p0) + relu + maxpool(2,2,p1) via MFMA -------
__global__ __launch_bounds__(256) void k_conv1_mfma(
    const float* __restrict__ data, const __hip_bfloat16* __restrict__ Aw1,
    const float* __restrict__ b1, __hip_bfloat16* __restrict__ P1t)
{
    __shared__ float tile[960];          // [ic]*312 + [rloc]*78 + [lc]; lc = x_in+1
    const int tid = threadIdx.x;
    const int py = blockIdx.x % 38, b = blockIdx.x / 38;

    #pragma unroll
    for (int c = 0; c < 4; c++) {
        int idx = tid + c * 256;
        if (idx < 960) {
            float val = 0.f;
            if (idx < 936) {
                int ic = idx / 312, rem = idx % 312;
                int rl = rem / 78, lc = rem % 78;
                int ri = 2 * py - 1 + rl, xi = lc - 1;
                if ((unsigned)ri < 76u && (unsigned)xi < 76u)
                    val = data[(b * 3 + ic) * 5776 + ri * 76 + xi];
            }
            tile[idx] = val;
        }
    }

    const int wave = tid >> 6, lane = tid & 63;
    const int l15 = lane & 15, quad = lane >> 4;

    bf16x8 af = *(const bf16x8*)((const ushort*)Aw1 + (wave * 16 + l15) * 32 + quad * 8);

    int koff[8]; bool kok[8];
    #pragma unroll
    for (int j = 0; j < 8; j++) {
        int kk = quad * 8 + j;
        kok[j] = kk < 27;
        int ic = kk / 9, rem = kk - ic * 9, ky = rem / 3, kx = rem - ky * 3;
        koff[j] = kok[j] ? (ic * 312 + ky * 78 + kx) : 0;
    }

    float bias[4];
    #pragma unroll
    for (int r = 0; r < 4; r++) bias[r] = b1[wave * 16 + quad * 4 + r];

    const bool valid0 = (py > 0);
    const bool valid1 = (py < 37);

    __syncthreads();

    #pragma unroll
    for (int t5 = 0; t5 < 5; t5++) {
        int n_x = t5 * 16 + l15;                         // conv x = n_x - 1
        bool col_ok = (unsigned)(n_x - 1) < 74u;

        bf16x8 bf0, bf1;
        #pragma unroll
        for (int j = 0; j < 8; j++) {
            float v0 = tile[koff[j] + n_x];
            float v1 = tile[koff[j] + 78 + n_x];
            bool ok = col_ok && kok[j];
            bf0[j] = (__bf16)(ok ? v0 : 0.f);
            bf1[j] = (__bf16)(ok ? v1 : 0.f);
        }
        f32x4 z = {0.f, 0.f, 0.f, 0.f};
        f32x4 c0 = __builtin_amdgcn_mfma_f32_16x16x32_bf16(af, bf0, z, 0, 0, 0);
        f32x4 c1 = __builtin_amdgcn_mfma_f32_16x16x32_bf16(af, bf1, z, 0, 0, 0);

        f32x4 p;
        #pragma unroll
        for (int r = 0; r < 4; r++) {
            float r0 = (valid0 && col_ok) ? fmaxf(c0[r] + bias[r], 0.f) : 0.f;
            float r1 = (valid1 && col_ok) ? fmaxf(c1[r] + bias[r], 0.f) : 0.f;
            p[r] = fmaxf(r0, r1);
        }
        #pragma unroll
        for (int r = 0; r < 4; r++)
            p[r] = fmaxf(p[r], __shfl_xor(p[r], 1));

        if (!(l15 & 1)) {
            int px = t5 * 8 + (l15 >> 1);
            if (px < 38) {
                ushort4 pk;
                pk.x = f2bf(p[0]); pk.y = f2bf(p[1]);
                pk.z = f2bf(p[2]); pk.w = f2bf(p[3]);
                *(ushort4*)((ushort*)P1t + ((size_t)(b * 38 + py) * 38 + px) * 64
                            + wave * 16 + quad * 4) = pk;
            }
        }
    }
}

// ---------------- conv2 + bias + relu + fused maxpool, 1-barrier form -----------
// Block = (b, band of 4 pooled rows, M-half). 320 threads = 5 waves (wn 0..4).
// LDS: P1t patch rows 2py0-2..2py0+7, cols -2..39, ic stride 72 (59 KB),
// staged once; K-loop reads B from patch, A from global (L2-hot), NO barriers.
// N=320: n = py_loc*80 + xc*2 + dy  (xc in [0,40) -> conv x = xc-1,
// conv y = 2(py0+py_loc)-1+dy). Pool quadruple = consecutive n (shfl_xor 1,2),
// lane n%4==0 stores P2t[b][py][px][oc]. K-order = round 11 => bit-identical.
__global__ __launch_bounds__(320) void k_conv2_pool_mfma(
    const __hip_bfloat16* __restrict__ P1t,   // [256][38][38][64]
    const __hip_bfloat16* __restrict__ Aw2,   // [128][576]
    const float* __restrict__ cb,             // [128]
    __hip_bfloat16* __restrict__ P2t)         // [256][20][20][128]
{
    __shared__ ushort patch[10 * 42 * 72];    // 60,480 B
    const int tid  = threadIdx.x;
    const int mh   = blockIdx.x & 1;
    const int tblk = blockIdx.x >> 1;
    const int band = tblk % 5, b = tblk / 5;
    const int py0  = band * 4;
    const int wn = tid >> 6, lane = tid & 63;
    const int l15 = lane & 15, quad = lane >> 4;

    // stage patch: input rows 2py0-2 .. 2py0+7, cols -2..39 (zero-padded)
    for (int i = tid; i < 3360; i += 320) {           // 10*42*8 uint4 chunks
        int pr = i / 336, rem = i % 336;
        int pcol = rem >> 3, c = rem & 7;
        int iy = 2 * py0 - 2 + pr, ix = pcol - 2;
        uint4 val = {0u, 0u, 0u, 0u};
        if ((unsigned)iy < 38u && (unsigned)ix < 38u)
            val = *(const uint4*)(P1t + (((b * 38 + iy) * 38 + ix) << 6) + c * 8);
        *(uint4*)(patch + (pr * 42 + pcol) * 72 + c * 8) = val;
    }

    // per-tn B decode (hoisted)
    int bbase[4]; bool vq[4];
    #pragma unroll
    for (int tn = 0; tn < 4; tn++) {
        int n = wn * 64 + tn * 16 + l15;
        int py_loc = n / 80, r80 = n % 80;
        int xc = r80 >> 1, dy = n & 1;
        bbase[tn] = (2 * py_loc + dy) * 42 + xc;      // patch (row, col) base
        int cy = 2 * (py0 + py_loc) - 1 + dy;
        int cx = xc - 1;
        vq[tn] = ((unsigned)cy < 38u) && ((unsigned)cx < 38u);
    }

    const ushort* Arow[4];
    #pragma unroll
    for (int tm = 0; tm < 4; tm++)
        Arow[tm] = (const ushort*)Aw2 + (size_t)(mh * 64 + tm * 16 + l15) * 576 + quad * 8;

    f32x4 zero = {0.f, 0.f, 0.f, 0.f};
    f32x4 acc[4][4];
    #pragma unroll
    for (int i = 0; i < 4; i++)
        #pragma unroll
        for (int j = 0; j < 4; j++) acc[i][j] = zero;

    __syncthreads();                                  // the ONLY barrier

    for (int kb = 0; kb < 9; kb++) {
        int ky = kb / 3, kx = kb - ky * 3;
        int rofs = (ky * 42 + kx) * 72 + quad * 8;
        bf16x8 af[2][4];
        #pragma unroll
        for (int kk = 0; kk < 2; kk++)
            #pragma unroll
            for (int tm = 0; tm < 4; tm++)
                af[kk][tm] = *(const bf16x8*)(Arow[tm] + kb * 64 + kk * 32);
        #pragma unroll
        for (int kk = 0; kk < 2; kk++) {
            bf16x8 bf[4];
            #pragma unroll
            for (int tn = 0; tn < 4; tn++)
                bf[tn] = *(const bf16x8*)(patch + bbase[tn] * 72 + rofs + kk * 32);
            #pragma unroll
            for (int tm = 0; tm < 4; tm++)
                #pragma unroll
                for (int tn = 0; tn < 4; tn++)
                    acc[tm][tn] = __builtin_amdgcn_mfma_f32_16x16x32_bf16(
                        af[kk][tm], bf[tn], acc[tm][tn], 0, 0, 0);
        }
    }

    // epilogue: relu(val+bias), zero invalid quadrants, pool via shfl, store n%4==0
    #pragma unroll
    for (int tn = 0; tn < 4; tn++) {
        int n = wn * 64 + tn * 16 + l15;
        #pragma unroll
        for (int tm = 0; tm < 4; tm++) {
            int m0 = mh * 64 + tm * 16 + quad * 4;
            f32x4 a = acc[tm][tn];
            f32x4 p;
            #pragma unroll
            for (int r = 0; r < 4; r++)
                p[r] = vq[tn] ? fmaxf(a[r] + cb[m0 + r], 0.f) : 0.f;
            #pragma unroll
            for (int r = 0; r < 4; r++) {
                p[r] = fmaxf(p[r], __shfl_xor(p[r], 1));
                p[r] = fmaxf(p[r], __shfl_xor(p[r], 2));
            }
            if ((l15 & 3) == 0) {
                int py = py0 + n / 80;
                int px = (n % 80) >> 2;
                ushort4 pk;
                pk.x = f2bf(p[0]); pk.y = f2bf(p[1]);
                pk.z = f2bf(p[2]); pk.w = f2bf(p[3]);
                *(ushort4*)((ushort*)P2t + (((size_t)b * 20 + py) * 20 + px) * 128 + m0) = pk;
            }
        }
    }
}

// ---------------- primcaps split-K MFMA GEMM, N=256 tile -> 6 fp32 partials ------
__global__ __launch_bounds__(512) void k_primcaps_mfma(
    const __hip_bfloat16* __restrict__ P2t,   // [256][20][20][128]
    const __hip_bfloat16* __restrict__ Awt,   // [256][10368]
    float* __restrict__ partU)                // [6][2359296]
{
    __shared__ ushort lA[128 * 72];           // 18,432 B
    __shared__ ushort lB[256 * 72];           // 36,864 B
    const int tid  = threadIdx.x;
    const int chunk = blockIdx.x / 72;
    const int tile  = blockIdx.x % 72;
    const int bm   = tile & 1;
    const int bn   = tile >> 1;               // 0..35
    const int wave = tid >> 6, lane = tid & 63;
    const int wm   = wave & 1, wn = wave >> 1;
    const int lane15 = lane & 15, quad = lane >> 4;

    const int arow = tid >> 2, apart = tid & 3;
    const int brow = tid >> 1, bpart = tid & 1;

    int n  = bn * 256 + brow;
    int cb = n / 36, cs = n % 36;
    int cy = cs / 6, cx = cs % 6;
    const __hip_bfloat16* Bbase = P2t + ((cb * 20 + 2 * cy) * 20 + 2 * cx) * 128;
    const __hip_bfloat16* Abase = Awt + (bm * 128 + arow) * 10368;
    ushort* lAw = &lA[arow * 72 + apart * 16];
    ushort* lBw = &lB[brow * 72 + bpart * 32];
    const ushort* aRd = &lA[(wm * 64 + lane15) * 72 + quad * 8];
    const ushort* bRd = &lB[(wn * 64 + lane15) * 72 + quad * 8];

    f32x4 zero = {0.f, 0.f, 0.f, 0.f};
    f32x4 acc[4][4];
    #pragma unroll
    for (int i = 0; i < 4; i++)
        #pragma unroll
        for (int j = 0; j < 4; j++) acc[i][j] = zero;

    const int kb0 = chunk * 27;
    for (int ki = 0; ki < 27; ki++) {
        int kb = kb0 + ki;
        int k81 = kb >> 1;
        int ky = k81 / 9, kx = k81 - ky * 9;
        int goffA = kb * 64 + apart * 16;
        int goffB = (ky * 20 + kx) * 128 + (kb & 1) * 64 + bpart * 32;

        const uint4* ga = (const uint4*)(Abase + goffA);
        const uint4* gb = (const uint4*)(Bbase + goffB);
        uint4 av0 = ga[0], av1 = ga[1];
        uint4 bv0 = gb[0], bv1 = gb[1], bv2 = gb[2], bv3 = gb[3];

        __syncthreads();
        ((uint4*)lAw)[0] = av0; ((uint4*)lAw)[1] = av1;
        ((uint4*)lBw)[0] = bv0; ((uint4*)lBw)[1] = bv1;
        ((uint4*)lBw)[2] = bv2; ((uint4*)lBw)[3] = bv3;
        __syncthreads();

        #pragma unroll
        for (int kk = 0; kk < 2; kk++) {
            bf16x8 af[4], bf[4];
            #pragma unroll
            for (int tm = 0; tm < 4; tm++)
                af[tm] = *(const bf16x8*)(aRd + tm * 16 * 72 + kk * 32);
            #pragma unroll
            for (int tn = 0; tn < 4; tn++)
                bf[tn] = *(const bf16x8*)(bRd + tn * 16 * 72 + kk * 32);
            #pragma unroll
            for (int tm = 0; tm < 4; tm++)
                #pragma unroll
                for (int tn = 0; tn < 4; tn++)
                    acc[tm][tn] = __builtin_amdgcn_mfma_f32_16x16x32_bf16(
                        af[tm], bf[tn], acc[tm][tn], 0, 0, 0);
        }
    }

    float* base = partU + chunk * 2359296;
    #pragma unroll
    for (int tm = 0; tm < 4; tm++) {
        int m0 = bm * 128 + wm * 64 + tm * 16 + quad * 4;
        #pragma unroll
        for (int tn = 0; tn < 4; tn++) {
            int nn = bn * 256 + wn * 64 + tn * 16 + lane15;
            int ob = nn / 36, os = nn % 36;
            float* up = base + ob * 9216 + os;
            f32x4 a = acc[tm][tn];
            #pragma unroll
            for (int r = 0; r < 4; r++)
                up[(m0 + r) * 36] = a[r];
        }
    }
}

// ---------------- reduce 6 partials + bias + squash -> u_bf [b][k] bf16 ----------
__global__ __launch_bounds__(256) void k_reduce_squash(
    const float* __restrict__ partU, const float* __restrict__ pb,
    ushort* __restrict__ u_bf)
{
    int t = blockIdx.x * 256 + threadIdx.x;              // 294912 threads
    float4 a = {0.f, 0.f, 0.f, 0.f}, b4 = {0.f, 0.f, 0.f, 0.f};
    #pragma unroll
    for (int p = 0; p < 6; p++) {
        const float4* pp = (const float4*)(partU + p * 2359296 + t * 8);
        float4 x = pp[0], y = pp[1];
        a.x += x.x; a.y += x.y; a.z += x.z; a.w += x.w;
        b4.x += y.x; b4.y += y.y; b4.z += y.z; b4.w += y.w;
    }
    int lb = (t % 1152) * 8;
    int oc0 = lb / 36, s0 = lb - oc0 * 36;
    float vals[8] = {a.x, a.y, a.z, a.w, b4.x, b4.y, b4.z, b4.w};
    float sn = 0.f;
    #pragma unroll
    for (int e = 0; e < 8; e++) {
        int oc = oc0 + ((s0 + e) >= 36 ? 1 : 0);
        vals[e] += pb[oc];
        sn += vals[e] * vals[e];
    }
    float sc = sqrtf(sn) / (1.f + sn);
    u16x8 o8;
    #pragma unroll
    for (int e = 0; e < 8; e++) o8[e] = f2bf(vals[e] * sc);
    *(u16x8*)(u_bf + (size_t)t * 8) = o8;
}

// ---------------- s_j with inline softmax ----------------
__global__ __launch_bounds__(320) void k_sj_fused(
    const ushort* __restrict__ u_bf,          // [256][9216] bf16
    const __hip_bfloat16* __restrict__ Wt,    // [9216][160] bf16
    const float* __restrict__ expb,           // [1152][10]
    float* __restrict__ partS,                // [16][256*160]
    int iter)
{
    __shared__ ushort ush[8 * 1152];
    __shared__ float cf[1440];
    __shared__ float sred[320];
    __shared__ float sinv[10];
    const int tid = threadIdx.x;
    const int bt = blockIdx.x & 31, kc = blockIdx.x >> 5;
    const int co = tid % 160, half = tid / 160;

    if (iter > 0) {
        int c = tid % 10, g = tid / 10;                  // 10 x 32 partition
        float s = 0.f;
        for (int r = g; r < 1152; r += 32) s += expb[r * 10 + c];
        sred[tid] = s;
        for (int i = tid; i < 1440; i += 320) cf[i] = expb[kc * 1440 + i];
        __syncthreads();
        if (tid < 10) {
            float t2 = 0.f;
            #pragma unroll
            for (int gg = 0; gg < 32; gg++) t2 += sred[tid + gg * 10];
            sinv[tid] = 1.f / t2;
        }
    }
    for (int i = tid; i < 1152; i += 320)     // 8 b x 144 uint4
        ((uint4*)ush)[i] = ((const uint4*)u_bf)[(size_t)(bt * 8 + (i / 144)) * 1152
                                                + kc * 144 + (i % 144)];
    __syncthreads();

    const int cc = co >> 4;
    const float scl = (iter > 0) ? sinv[cc] : 0.f;
    const float cuni = 1.f / 1152.f;
    const ushort* wp = (const ushort*)Wt + ((size_t)kc * 1152 + half * 576) * 160 + co;

    float acc[8] = {0.f, 0.f, 0.f, 0.f, 0.f, 0.f, 0.f, 0.f};
    for (int rr = 0; rr < 72; rr++) {
        float cl = (iter == 0) ? cuni : cf[(half * 72 + rr) * 10 + cc] * scl;
        float wv[8];
        #pragma unroll
        for (int ii = 0; ii < 8; ii++)
            wv[ii] = b2f(wp[(rr * 8 + ii) * 160]) * cl;
        int kbase = half * 576 + rr * 8;
        #pragma unroll
        for (int bb = 0; bb < 8; bb++) {
            u16x8 uq = *(const u16x8*)&ush[bb * 1152 + kbase];
            #pragma unroll
            for (int ii = 0; ii < 8; ii++)
                acc[bb] += wv[ii] * b2f(uq[ii]);
        }
    }
    float* ps = partS + (kc * 2 + half) * 40960;
    #pragma unroll
    for (int bb = 0; bb < 8; bb++)
        ps[(bt * 8 + bb) * 160 + co] = acc[bb];
}

// ---------------- v = squash(sum partS); final iter also runs classifiers -------
__global__ __launch_bounds__(320) void k_vj_cls(
    const float* __restrict__ partS, float* __restrict__ v,
    const float* __restrict__ w1, const float* __restrict__ b1,
    const float* __restrict__ w2, const float* __restrict__ b2,
    float* __restrict__ out, int write_out)
{
    const int b = blockIdx.x;
    const int tid = threadIdx.x;
    __shared__ float feat[160];
    if (tid < 160) {
        float s = 0.f;
        #pragma unroll
        for (int p = 0; p < 16; p++) s += partS[p * 40960 + b * 160 + tid];
        float vv = s * fabsf(s) / (1.f + s * s);
        v[b * 160 + tid] = vv;
        feat[tid] = vv;
        if (write_out) out[b * 160 + tid] = vv;
    }
    if (!write_out) return;
    __syncthreads();
    int k = tid >> 5, j = tid & 31;                      // 10 classifiers x 32 lanes
    float acc = 0.f;
    for (int h = j; h < 100; h += 32) {
        float a = b1[k * 100 + h];
        for (int f = 0; f < 160; f++) a += feat[f] * w1[(k * 160 + f) * 100 + h];
        acc += fmaxf(a, 0.f) * w2[k * 100 + h];
    }
    #pragma unroll
    for (int d = 16; d > 0; d >>= 1) acc += __shfl_xor(acc, d);
    if (j == 0)
        out[40960 + b * 10 + k] = 1.f / (1.f + expf(-(acc + b2[k])));
}

// ---------------- M rows for route r + a_ij + bij update + expb -----------------
__global__ __launch_bounds__(320) void k_mmat_aij(
    const ushort* __restrict__ u_bf, const float* __restrict__ v,
    const float* __restrict__ W, float* __restrict__ bij,
    float* __restrict__ expb)
{
    const int r = blockIdx.x;
    const int tid = threadIdx.x;
    const int co = tid % 160, bh = tid / 160;
    float acc[8] = {0.f, 0.f, 0.f, 0.f, 0.f, 0.f, 0.f, 0.f};
    for (int b = bh; b < 256; b += 2) {
        float vv = v[b * 160 + co];
        u16x8 uq = *(const u16x8*)(u_bf + (size_t)b * 9216 + r * 8);
        #pragma unroll
        for (int j = 0; j < 8; j++) acc[j] += vv * b2f(uq[j]);
    }
    __shared__ float red[2560];               // [j][bh][co]
    __shared__ float Ml[8][160];
    #pragma unroll
    for (int j = 0; j < 8; j++) red[j * 320 + bh * 160 + co] = acc[j];
    __syncthreads();
    if (tid < 160) {
        #pragma unroll
        for (int j = 0; j < 8; j++)
            Ml[j][tid] = (red[j * 320 + tid] + red[j * 320 + 160 + tid]) * (1.f / 256.f);
    }
    __syncthreads();
    int c = tid >> 5, j32 = tid & 31;                    // 10 c x 32 lanes
    const float* wr = W + ((size_t)r * 10 + c) * 128;    // W[r][c][o][i] flat
    float a2 = 0.f;
    #pragma unroll
    for (int m = 0; m < 4; m++) {
        int idx = j32 + m * 32;                          // = o*8 + i
        int o = idx >> 3, i = idx & 7;
        a2 += wr[idx] * Ml[i][c * 16 + o];
    }
    #pragma unroll
    for (int d = 16; d > 0; d >>= 1) a2 += __shfl_xor(a2, d);
    if (j32 == 0) {
        float nb = bij[c * 1152 + r] + a2;
        bij[c * 1152 + r] = nb;
        expb[r * 10 + c] = expf(nb);
    }
}

extern "C" void kernel_launch(void* const* d_in, const int* in_sizes, int n_in,
                              void* d_out, int out_size, void* d_ws, size_t ws_size,
                              hipStream_t stream) {
    const float* data    = (const float*)d_in[0];
    const float* conv1_w = (const float*)d_in[1];
    const float* conv1_b = (const float*)d_in[2];
    const float* conv2_w = (const float*)d_in[3];
    const float* conv2_b = (const float*)d_in[4];
    const float* prim_w  = (const float*)d_in[5];
    const float* prim_b  = (const float*)d_in[6];
    const float* W       = (const float*)d_in[7];
    const float* cls_w1  = (const float*)d_in[8];
    const float* cls_b1  = (const float*)d_in[9];
    const float* cls_w2  = (const float*)d_in[10];
    const float* cls_b2  = (const float*)d_in[11];
    float* out = (float*)d_out;

    char* ws = (char*)d_ws;
    // No region aliasing: conv2+pool reads P1t / writes P2t (disjoint);
    // primcaps reads P2t / writes partU (disjoint).
    float*          partU = (float*)(ws + 0);                   // 56,623,104
    __hip_bfloat16* P2t   = (__hip_bfloat16*)(ws + 56623104);   // 13,107,200
    __hip_bfloat16* P1t   = (__hip_bfloat16*)(ws + 94633984);   // 47,316,992
    __hip_bfloat16* Awt   = (__hip_bfloat16*)(ws + 141950976);  //  5,308,416
    __hip_bfloat16* Wt    = (__hip_bfloat16*)(ws + 147259392);  //  2,949,120
    ushort*         u_bf  = (ushort*)(ws + 150208512);          //  4,718,592
    float*          partS = (float*)(ws + 154927104);           //  2,621,440
    float*          v     = (float*)(ws + 163446784);           //    163,840
    float*          bij   = (float*)(ws + 163610624);           //     46,080
    float*          expb  = (float*)(ws + 163656704);           //     46,080
    __hip_bfloat16* Aw2   = (__hip_bfloat16*)(ws + 163702784);  //    147,456
    __hip_bfloat16* Aw1   = (__hip_bfloat16*)(ws + 163850240);  //      4,096
    // total: 163,854,336 bytes

    hipMemsetAsync(bij, 0, 11520 * sizeof(float), stream);

    k_prep_all<<<16424, 256, 0, stream>>>(conv1_w, conv2_w, prim_w, W,
                                          Aw1, Aw2, Awt, Wt);
    k_conv1_mfma<<<9728, 256, 0, stream>>>(data, Aw1, conv1_b, P1t);
    k_conv2_pool_mfma<<<2560, 320, 0, stream>>>(P1t, Aw2, conv2_b, P2t);
    k_primcaps_mfma<<<432, 512, 0, stream>>>(P2t, Awt, partU);
    k_reduce_squash<<<1152, 256, 0, stream>>>(partU, prim_b, u_bf);

    for (int it = 0; it < 3; it++) {
        k_sj_fused<<<256, 320, 0, stream>>>(u_bf, Wt, expb, partS, it);
        k_vj_cls<<<256, 320, 0, stream>>>(partS, v, cls_w1, cls_b1, cls_w2,
                                          cls_b2, out, it == 2 ? 1 : 0);
        if (it < 2)
            k_mmat_aij<<<1152, 320, 0, stream>>>(u_bf, v, W, bij, expb);
    }
}